// Round 6
// baseline (1315.309 us; speedup 1.0000x reference)
//
#include <hip/hip_runtime.h>

// Shapes
constexpr int Bb = 16, Nn = 512, Cc = 64, Tt = 12, Hh = 64;
constexpr int NCT = Nn * Cc * Tt;     // 393216
constexpr int CT  = Cc * Tt;          // 768

// ---------------------------------------------------------------------------
// K0: transpose res_w [H][C] -> resT [C][H]
__global__ void k0_rest(const float* __restrict__ rw, float* __restrict__ resT) {
    int i = blockIdx.x * 256 + threadIdx.x;        // i = h*64 + c
    if (i < Hh * Cc) {
        int h = i >> 6, c = i & 63;
        resT[c * 64 + h] = rw[i];
    }
}

// ---------------------------------------------------------------------------
// K1a: tmp1[b][c*12+t] = sum_n x[b,n,c,t] * U1[n]   (partial over n-chunk, atomic)
__global__ void k1a_tmp1(const float* __restrict__ x, const float* __restrict__ U1,
                         float* __restrict__ tmp1) {
    int blk = blockIdx.x;                 // 16 * 3 * 4 = 192
    int b = blk / 12; int r = blk % 12;
    int ctb = r >> 2; int nch = r & 3;
    int ct = ctb * 256 + threadIdx.x;
    const float* xb = x + (size_t)b * NCT;
    float acc = 0.f;
    int n0 = nch * 128;
    for (int n = n0; n < n0 + 128; ++n)
        acc += xb[n * CT + ct] * U1[n];
    atomicAdd(&tmp1[b * CT + ct], acc);
}

// K1b: rhs[b][n][t] = sum_c U3[c] * x[b,n,c,t]  — one wave per (b,n), coalesced
__global__ void k1b_rhs(const float* __restrict__ x, const float* __restrict__ U3,
                        float* __restrict__ rhs) {
    int wid = blockIdx.x * 4 + (threadIdx.x >> 6);   // 8192 waves = B*N
    int b = wid >> 9; int n = wid & 511;
    int l = threadIdx.x & 63;
    const float4* x4 = (const float4*)(x + (size_t)(b * Nn + n) * CT);
    float4 a0 = x4[3 * l], a1 = x4[3 * l + 1], a2 = x4[3 * l + 2];  // channel l, t=0..11
    float xv[12] = {a0.x,a0.y,a0.z,a0.w, a1.x,a1.y,a1.z,a1.w, a2.x,a2.y,a2.z,a2.w};
    float u = U3[l];
    float p[12];
    #pragma unroll
    for (int t = 0; t < 12; ++t) p[t] = u * xv[t];
    #pragma unroll
    for (int off = 1; off < 64; off <<= 1) {
        #pragma unroll
        for (int t = 0; t < 12; ++t) p[t] += __shfl_xor(p[t], off);
    }
    if (l == 0) {
        float* rp = rhs + (size_t)(b * Nn + n) * 12;
        *(float4*)(rp)     = make_float4(p[0], p[1], p[2], p[3]);
        *(float4*)(rp + 4) = make_float4(p[4], p[5], p[6], p[7]);
        *(float4*)(rp + 8) = make_float4(p[8], p[9], p[10], p[11]);
    }
}

// K1c: per-batch: lhs, product, E, softmax -> At[b][12][12]
__global__ void k1c_att(const float* __restrict__ tmp1, const float* __restrict__ rhs,
                        const float* __restrict__ U2, const float* __restrict__ be,
                        const float* __restrict__ Ve, float* __restrict__ At) {
    __shared__ float t1[CT];
    __shared__ float rh[Nn * Tt];
    __shared__ float lh[Tt * Nn];
    __shared__ float part[576];
    __shared__ float sp[144];
    __shared__ float Ee[144];
    int b = blockIdx.x, tid = threadIdx.x;
    for (int i = tid; i < CT; i += 256) t1[i] = tmp1[b * CT + i];
    for (int i = tid; i < Nn * Tt; i += 256) rh[i] = rhs[b * Nn * Tt + i];
    __syncthreads();
    for (int nn = tid; nn < Nn; nn += 256) {
        float l[Tt];
        #pragma unroll
        for (int t = 0; t < Tt; ++t) l[t] = 0.f;
        for (int c = 0; c < Cc; ++c) {
            float u2 = U2[c * Nn + nn];
            #pragma unroll
            for (int t = 0; t < Tt; ++t) l[t] += t1[c * Tt + t] * u2;
        }
        #pragma unroll
        for (int t = 0; t < Tt; ++t) lh[t * Nn + nn] = l[t];
    }
    __syncthreads();
    for (int task = tid; task < 576; task += 256) {
        int ts = task >> 2, ch = task & 3;
        int t = ts / 12, s2 = ts % 12;
        int n0 = ch * 128;
        float a = 0.f;
        for (int nn = n0; nn < n0 + 128; ++nn) a += lh[t * Nn + nn] * rh[nn * Tt + s2];
        part[task] = a;
    }
    __syncthreads();
    if (tid < 144) {
        float a = part[tid * 4] + part[tid * 4 + 1] + part[tid * 4 + 2] + part[tid * 4 + 3]
                + be[tid];
        sp[tid] = 1.f / (1.f + __expf(-a));
    }
    __syncthreads();
    if (tid < 144) {
        int i = tid / 12, k = tid % 12;
        float a = 0.f;
        #pragma unroll
        for (int j = 0; j < 12; ++j) a += Ve[i * 12 + j] * sp[j * 12 + k];
        Ee[tid] = a;
    }
    __syncthreads();
    if (tid < 12) {
        int k = tid;
        float mx = -1e30f;
        #pragma unroll
        for (int i = 0; i < 12; ++i) mx = fmaxf(mx, Ee[i * 12 + k]);
        float su = 0.f; float ex[12];
        #pragma unroll
        for (int i = 0; i < 12; ++i) { ex[i] = __expf(Ee[i * 12 + k] - mx); su += ex[i]; }
        float inv = 1.f / su;
        #pragma unroll
        for (int i = 0; i < 12; ++i) At[b * 144 + i * 12 + k] = ex[i] * inv;
    }
}

// ---------------------------------------------------------------------------
// K2: xtT[b][t][c][n] = sum_tau x[b,n,c,tau] * At[b,tau,t]
__global__ void k2_xtt(const float* __restrict__ x, const float* __restrict__ At,
                       float* __restrict__ xtT) {
    int idx = blockIdx.x * 256 + threadIdx.x;  // B*C*N = 524288, n fastest
    int n = idx & 511; int c = (idx >> 9) & 63; int b = idx >> 15;
    const float* xr = x + (size_t)((b * Nn + n) * Cc + c) * Tt;
    float xv[Tt];
    {
        const float4* x4 = (const float4*)xr;
        float4 a0 = x4[0], a1 = x4[1], a2 = x4[2];
        xv[0]=a0.x; xv[1]=a0.y; xv[2]=a0.z; xv[3]=a0.w;
        xv[4]=a1.x; xv[5]=a1.y; xv[6]=a1.z; xv[7]=a1.w;
        xv[8]=a2.x; xv[9]=a2.y; xv[10]=a2.z; xv[11]=a2.w;
    }
    const float* Ab = At + b * 144;
    for (int t = 0; t < Tt; ++t) {
        float a = 0.f;
        #pragma unroll
        for (int u = 0; u < Tt; ++u) a += xv[u] * Ab[u * 12 + t];
        xtT[((size_t)(b * Tt + t) * Cc + c) * Nn + n] = a;
    }
}

// K2b: enhT[t][m][n] = adj[n][m] * sigmoid(masks[t][n][m])  (tiled transpose)
__global__ void k2b_enh(const float* __restrict__ adj, const float* __restrict__ masks,
                        float* __restrict__ enhT) {
    __shared__ float tile[32][33];
    int blk = blockIdx.x;              // 12 * 16 * 16 = 3072
    int t = blk >> 8; int r = blk & 255;
    int n0 = (r >> 4) * 32; int m0 = (r & 15) * 32;
    int tx = threadIdx.x & 31; int ty = threadIdx.x >> 5;   // ty 0..7
    #pragma unroll
    for (int i = 0; i < 4; ++i) {
        int nl = ty + 8 * i;
        float a  = adj[(n0 + nl) * Nn + m0 + tx];
        float mk = masks[t * Nn * Nn + (n0 + nl) * Nn + m0 + tx];
        tile[nl][tx] = a / (1.f + __expf(-mk));
    }
    __syncthreads();
    #pragma unroll
    for (int i = 0; i < 4; ++i) {
        int ml = ty + 8 * i;
        enhT[(size_t)(t * Nn + m0 + ml) * Nn + n0 + tx] = tile[tx][ml];
    }
}

// ---------------------------------------------------------------------------
// K3: c-split x4 — each row n handled by 4 lanes (cg=lane>>4), each owning 16
// channels. m4-column cached in regs (v[16]) and reused for score AND both
// accumulations -> 16 ds_read_b128 per lane per m4 (12 FMA each). State 48
// floats -> no spill. Grid 1536 (B*T*8), block 256 (64 rows).
__global__ __launch_bounds__(256, 3) void k3_gcn(
    const float* __restrict__ xtT, const float* __restrict__ enhT,
    const float* __restrict__ W0, const float* __restrict__ b0,
    const float* __restrict__ Ws, const float* __restrict__ bs,
    const float* __restrict__ Wd, const float* __restrict__ bd,
    float* __restrict__ F) {
    __shared__ float xs[64][64];       // [c][m-tile] 16 KB
    int blk = blockIdx.x;              // 1536 = B*T*8
    int seg = blk & 7; int t = (blk >> 3) % Tt; int b = blk / (Tt * 8);
    int tid = threadIdx.x;
    int lane = tid & 63;
    int w = tid >> 6;                  // wave 0..3
    int cg = lane >> 4;                // c-group 0..3
    int r = lane & 15;
    int n = seg * 64 + w * 16 + r;
    int c0 = cg * 16;
    const float* xb = xtT + (size_t)(b * Tt + t) * Cc * Nn;  // [C][N]
    float row[16], accd[16], accs[16];
    #pragma unroll
    for (int j = 0; j < 16; ++j) row[j] = xb[(c0 + j) * Nn + n];
    #pragma unroll
    for (int j = 0; j < 16; ++j) { accd[j] = 0.f; accs[j] = 0.f; }
    float sumexp = 0.f;
    const float* ehT = enhT + (size_t)t * Nn * Nn + n;       // [m][n], n per-lane
    for (int m0 = 0; m0 < Nn; m0 += 64) {
        __syncthreads();               // previous tile fully consumed
        #pragma unroll
        for (int i = 0; i < 4; ++i) {
            int f = i * 256 + tid;     // float4 index 0..1023
            int c = f >> 4; int mi = (f & 15) * 4;
            *(float4*)&xs[c][mi] = *(const float4*)(xb + c * Nn + m0 + mi);
        }
        __syncthreads();
        #pragma unroll 1
        for (int m4 = 0; m4 < 64; m4 += 4) {
            float e0 = ehT[(m0 + m4 + 0) * Nn];
            float e1 = ehT[(m0 + m4 + 1) * Nn];
            float e2 = ehT[(m0 + m4 + 2) * Nn];
            float e3 = ehT[(m0 + m4 + 3) * Nn];
            float4 v[16];
            #pragma unroll
            for (int j = 0; j < 16; ++j) v[j] = *(const float4*)&xs[c0 + j][m4];
            float s0 = 0.f, s1 = 0.f, s2 = 0.f, s3 = 0.f;
            #pragma unroll
            for (int j = 0; j < 16; ++j) {
                float rj = row[j];
                s0 += rj * v[j].x; s1 += rj * v[j].y;
                s2 += rj * v[j].z; s3 += rj * v[j].w;
            }
            s0 += __shfl_xor(s0, 16); s0 += __shfl_xor(s0, 32);
            s1 += __shfl_xor(s1, 16); s1 += __shfl_xor(s1, 32);
            s2 += __shfl_xor(s2, 16); s2 += __shfl_xor(s2, 32);
            s3 += __shfl_xor(s3, 16); s3 += __shfl_xor(s3, 32);
            float p0 = __expf(s0 * 0.125f), p1 = __expf(s1 * 0.125f);
            float p2 = __expf(s2 * 0.125f), p3 = __expf(s3 * 0.125f);
            sumexp += (p0 + p1) + (p2 + p3);
            #pragma unroll
            for (int j = 0; j < 16; ++j) {
                accd[j] += p0 * v[j].x + p1 * v[j].y + p2 * v[j].z + p3 * v[j].w;
                accs[j] += e0 * v[j].x + e1 * v[j].y + e2 * v[j].z + e3 * v[j].w;
            }
        }
    }
    float invd = 0.475f / sumexp;
    #pragma unroll
    for (int j = 0; j < 16; ++j) {
        accd[j] *= invd; accs[j] *= 0.475f; row[j] *= 0.05f;
    }
    const float* Wst = Ws + t * Hh * Cc;
    const float* Wdt = Wd + t * Hh * Cc;
    float* Fp = F + ((size_t)(b * Tt + t) * Nn + n) * Hh;
    for (int hb = 0; hb < 16; ++hb) {
        float oo[4];
        #pragma unroll
        for (int k = 0; k < 4; ++k) {
            int h = hb * 4 + k;
            const float4* w04 = (const float4*)(W0 + h * Cc + c0);
            const float4* ws4 = (const float4*)(Wst + h * Cc + c0);
            const float4* wd4 = (const float4*)(Wdt + h * Cc + c0);
            float a = 0.f;
            #pragma unroll
            for (int jj = 0; jj < 4; ++jj) {
                float4 wv = w04[jj], sv = ws4[jj], dv = wd4[jj];
                a += row[jj*4+0]*wv.x + row[jj*4+1]*wv.y + row[jj*4+2]*wv.z + row[jj*4+3]*wv.w;
                a += accs[jj*4+0]*sv.x + accs[jj*4+1]*sv.y + accs[jj*4+2]*sv.z + accs[jj*4+3]*sv.w;
                a += accd[jj*4+0]*dv.x + accd[jj*4+1]*dv.y + accd[jj*4+2]*dv.z + accd[jj*4+3]*dv.w;
            }
            a += __shfl_xor(a, 16);
            a += __shfl_xor(a, 32);
            oo[k] = a + 0.05f * b0[h] + 0.475f * (bs[t * Hh + h] + bd[t * Hh + h]);
        }
        if ((hb >> 2) == cg)
            *(float4*)(Fp + hb * 4) = make_float4(oo[0], oo[1], oo[2], oo[3]);
    }
}

// ---------------------------------------------------------------------------
// K4: multi-scale grouped conv over t + GN statistics (4 nodes/block)
__global__ __launch_bounds__(512) void k4_conv(
                        const float* __restrict__ F,
                        const float* __restrict__ w3, const float* __restrict__ w5,
                        const float* __restrict__ w7, const float* __restrict__ w9,
                        const float* __restrict__ cb,
                        float* __restrict__ xc, float* __restrict__ stats) {
    __shared__ float fl[4 * Tt * Hh];   // [t][nl][h] = 3072
    __shared__ float sstat[64];
    int blk = blockIdx.x;               // B * N/4 = 2048
    int b = blk >> 7; int n0 = (blk & 127) * 4;
    int tid = threadIdx.x;
    if (tid < 64) sstat[tid] = 0.f;
    for (int i = tid; i < 3072; i += 512) {
        int t = i >> 8; int r = i & 255;
        fl[i] = F[(size_t)(b * Tt + t) * Nn * Hh + n0 * Hh + r];
    }
    __syncthreads();
    int nl = tid >> 7; int co = tid & 127;
    int g = co >> 5;
    float a3[10], a5[8], a7[6], a9[4];
    {
        float c3 = cb[co], c5 = cb[128 + co], c7 = cb[256 + co], c9 = cb[384 + co];
        #pragma unroll
        for (int j = 0; j < 10; ++j) a3[j] = c3;
        #pragma unroll
        for (int j = 0; j < 8; ++j) a5[j] = c5;
        #pragma unroll
        for (int j = 0; j < 6; ++j) a7[j] = c7;
        #pragma unroll
        for (int j = 0; j < 4; ++j) a9[j] = c9;
    }
    for (int ci = 0; ci < 16; ++ci) {
        int cig = g * 16 + ci;
        float xr[12];
        #pragma unroll
        for (int tt = 0; tt < 12; ++tt) xr[tt] = fl[tt * 256 + nl * 64 + cig];
        const float* p3 = w3 + (co * 16 + ci) * 3;
        #pragma unroll
        for (int dt = 0; dt < 3; ++dt) {
            float wv = p3[dt];
            #pragma unroll
            for (int j = 0; j < 10; ++j) a3[j] += xr[j + dt] * wv;
        }
        const float* p5 = w5 + (co * 16 + ci) * 5;
        #pragma unroll
        for (int dt = 0; dt < 5; ++dt) {
            float wv = p5[dt];
            #pragma unroll
            for (int j = 0; j < 8; ++j) a5[j] += xr[j + dt] * wv;
        }
        const float* p7 = w7 + (co * 16 + ci) * 7;
        #pragma unroll
        for (int dt = 0; dt < 7; ++dt) {
            float wv = p7[dt];
            #pragma unroll
            for (int j = 0; j < 6; ++j) a7[j] += xr[j + dt] * wv;
        }
        const float* p9 = w9 + (co * 16 + ci) * 9;
        #pragma unroll
        for (int dt = 0; dt < 9; ++dt) {
            float wv = p9[dt];
            #pragma unroll
            for (int j = 0; j < 4; ++j) a9[j] += xr[j + dt] * wv;
        }
    }
    int pg = (co < 64) ? (co >> 4) : 4 + ((co - 64) >> 4);
    float* xcw = xc + ((size_t)(b * Nn + n0 + nl) * 128 + co) * 28;
    float su, sq;
    // scale 0 (k=3)
    su = 0.f; sq = 0.f;
    #pragma unroll
    for (int j = 0; j < 10; ++j) { float v = a3[j]; xcw[j] = v; su += v; sq += v * v; }
    #pragma unroll
    for (int off = 1; off < 16; off <<= 1) { su += __shfl_xor(su, off); sq += __shfl_xor(sq, off); }
    if ((tid & 15) == 0) { atomicAdd(&sstat[(0 * 8 + pg) * 2], su); atomicAdd(&sstat[(0 * 8 + pg) * 2 + 1], sq); }
    // scale 1 (k=5)
    su = 0.f; sq = 0.f;
    #pragma unroll
    for (int j = 0; j < 8; ++j) { float v = a5[j]; xcw[10 + j] = v; su += v; sq += v * v; }
    #pragma unroll
    for (int off = 1; off < 16; off <<= 1) { su += __shfl_xor(su, off); sq += __shfl_xor(sq, off); }
    if ((tid & 15) == 0) { atomicAdd(&sstat[(1 * 8 + pg) * 2], su); atomicAdd(&sstat[(1 * 8 + pg) * 2 + 1], sq); }
    // scale 2 (k=7)
    su = 0.f; sq = 0.f;
    #pragma unroll
    for (int j = 0; j < 6; ++j) { float v = a7[j]; xcw[18 + j] = v; su += v; sq += v * v; }
    #pragma unroll
    for (int off = 1; off < 16; off <<= 1) { su += __shfl_xor(su, off); sq += __shfl_xor(sq, off); }
    if ((tid & 15) == 0) { atomicAdd(&sstat[(2 * 8 + pg) * 2], su); atomicAdd(&sstat[(2 * 8 + pg) * 2 + 1], sq); }
    // scale 3 (k=9)
    su = 0.f; sq = 0.f;
    #pragma unroll
    for (int j = 0; j < 4; ++j) { float v = a9[j]; xcw[24 + j] = v; su += v; sq += v * v; }
    #pragma unroll
    for (int off = 1; off < 16; off <<= 1) { su += __shfl_xor(su, off); sq += __shfl_xor(sq, off); }
    if ((tid & 15) == 0) { atomicAdd(&sstat[(3 * 8 + pg) * 2], su); atomicAdd(&sstat[(3 * 8 + pg) * 2 + 1], sq); }
    __syncthreads();
    if (tid < 64) {
        int s = tid >> 4; int pgq = (tid >> 1) & 7; int st = tid & 1;
        atomicAdd(&stats[((s * Bb + b) * 8 + pgq) * 2 + st], sstat[(s * 8 + pgq) * 2 + st]);
    }
}

// ---------------------------------------------------------------------------
// K5: GN + Mish*Hardtanh + fc + residual + LN -> out[b][n][h][t]
__global__ __launch_bounds__(256) void k5_final(
                         const float* __restrict__ xc, const float* __restrict__ stats,
                         const float* __restrict__ x,
                         const float* __restrict__ gpw, const float* __restrict__ gpb,
                         const float* __restrict__ gqw, const float* __restrict__ gqb,
                         const float* __restrict__ fcw, const float* __restrict__ fcb,
                         const float* __restrict__ resT, const float* __restrict__ rb,
                         const float* __restrict__ lnw, const float* __restrict__ lnb,
                         float* __restrict__ out) {
    int blk = blockIdx.x;               // 2048 = B * N/4
    int b = blk >> 7; int n = (blk & 127) * 4 + (threadIdx.x >> 6);
    int h = threadIdx.x & 63;
    int pg = h >> 4;
    const int TkA[4] = {10, 8, 6, 4};
    float mu_p[4], rs_p[4], mu_q[4], rs_q[4];
    #pragma unroll
    for (int s = 0; s < 4; ++s) {
        float cnt = 16.f * 512.f * (float)TkA[s];
        float su = stats[((s * Bb + b) * 8 + pg) * 2];
        float sq = stats[((s * Bb + b) * 8 + pg) * 2 + 1];
        float mu = su / cnt; float var = sq / cnt - mu * mu;
        mu_p[s] = mu; rs_p[s] = rsqrtf(var + 1e-5f);
        su = stats[((s * Bb + b) * 8 + 4 + pg) * 2];
        sq = stats[((s * Bb + b) * 8 + 4 + pg) * 2 + 1];
        mu = su / cnt; var = sq / cnt - mu * mu;
        mu_q[s] = mu; rs_q[s] = rsqrtf(var + 1e-5f);
    }
    const float* xcp = xc + ((size_t)(b * Nn + n) * 128 + h) * 28;
    const float* xcq = xcp + 64 * 28;
    float pb_[28], qb_[28];
    {
        const float4* p4 = (const float4*)xcp;
        const float4* q4 = (const float4*)xcq;
        #pragma unroll
        for (int j = 0; j < 7; ++j) {
            float4 a = p4[j];
            pb_[j*4] = a.x; pb_[j*4+1] = a.y; pb_[j*4+2] = a.z; pb_[j*4+3] = a.w;
            float4 c = q4[j];
            qb_[j*4] = c.x; qb_[j*4+1] = c.y; qb_[j*4+2] = c.z; qb_[j*4+3] = c.w;
        }
    }
    float tc[28];
    int off = 0;
    #pragma unroll
    for (int s = 0; s < 4; ++s) {
        float pw = gpw[s * 64 + h], pbv = gpb[s * 64 + h];
        float qw = gqw[s * 64 + h], qbv = gqb[s * 64 + h];
        #pragma unroll
        for (int j = 0; j < 10; ++j) {
            if (j < TkA[s]) {
                float p = (pb_[off + j] - mu_p[s]) * rs_p[s] * pw + pbv;
                float q = (qb_[off + j] - mu_q[s]) * rs_q[s] * qw + qbv;
                // mish(p) = p * tanh(softplus(p)); tanh(sp) = (z^2-1)/(z^2+1), z = 1+e^p
                float mish;
                if (p > 20.f) mish = p;
                else { float z = 1.f + __expf(p); float z2 = z * z; mish = p * (z2 - 1.f) / (z2 + 1.f); }
                float gate = fminf(fmaxf(q, 0.f), 1.f);
                tc[off + j] = mish * gate;
            }
        }
        off += TkA[s];
    }
    float o[12];
    #pragma unroll
    for (int t = 0; t < 12; ++t) {
        float a = fcb[t];
        #pragma unroll
        for (int k = 0; k < 28; ++k) a += tc[k] * fcw[t * 28 + k];
        o[t] = fmaxf(a, 0.f);
    }
    const float* xr = x + (size_t)(b * Nn + n) * CT;
    float res[12];
    float rbv = rb[h];
    #pragma unroll
    for (int t = 0; t < 12; ++t) res[t] = rbv;
    for (int c = 0; c < 64; ++c) {
        float rv = resT[c * 64 + h];
        #pragma unroll
        for (int t = 0; t < 12; ++t) res[t] += xr[c * 12 + t] * rv;
    }
    float y[12];
    #pragma unroll
    for (int t = 0; t < 12; ++t) y[t] = fmaxf(res[t] + o[t], 0.f);
    float lw = lnw[h], lb = lnb[h];
    float ov[12];
    #pragma unroll
    for (int t = 0; t < 12; ++t) {
        float s1 = y[t], s2 = y[t] * y[t];
        #pragma unroll
        for (int o2 = 32; o2 > 0; o2 >>= 1) {
            s1 += __shfl_xor(s1, o2);
            s2 += __shfl_xor(s2, o2);
        }
        float mu = s1 * (1.f / 64.f);
        float var = s2 * (1.f / 64.f) - mu * mu;
        ov[t] = (y[t] - mu) * rsqrtf(var + 1e-5f) * lw + lb;
    }
    float* op = out + ((size_t)(b * Nn + n) * Hh + h) * Tt;
    *(float4*)(op)     = make_float4(ov[0], ov[1], ov[2], ov[3]);
    *(float4*)(op + 4) = make_float4(ov[4], ov[5], ov[6], ov[7]);
    *(float4*)(op + 8) = make_float4(ov[8], ov[9], ov[10], ov[11]);
}

// ---------------------------------------------------------------------------
extern "C" void kernel_launch(void* const* d_in, const int* in_sizes, int n_in,
                              void* d_out, int out_size, void* d_ws, size_t ws_size,
                              hipStream_t stream) {
    const float* x    = (const float*)d_in[0];
    const float* adj  = (const float*)d_in[1];
    const float* U1   = (const float*)d_in[2];
    const float* U2   = (const float*)d_in[3];
    const float* U3   = (const float*)d_in[4];
    const float* be   = (const float*)d_in[5];
    const float* Ve   = (const float*)d_in[6];
    const float* W0   = (const float*)d_in[7];
    const float* b0   = (const float*)d_in[8];
    const float* masks= (const float*)d_in[9];
    const float* Ws   = (const float*)d_in[10];
    const float* bs   = (const float*)d_in[11];
    const float* Wd   = (const float*)d_in[12];
    const float* bd   = (const float*)d_in[13];
    const float* w3   = (const float*)d_in[14];
    const float* w5   = (const float*)d_in[15];
    const float* w7   = (const float*)d_in[16];
    const float* w9   = (const float*)d_in[17];
    const float* cb   = (const float*)d_in[18];
    const float* gpw  = (const float*)d_in[19];
    const float* gpb  = (const float*)d_in[20];
    const float* gqw  = (const float*)d_in[21];
    const float* gqb  = (const float*)d_in[22];
    const float* fcw  = (const float*)d_in[23];
    const float* fcb  = (const float*)d_in[24];
    const float* rw   = (const float*)d_in[25];
    const float* rb   = (const float*)d_in[26];
    const float* lnw  = (const float*)d_in[27];
    const float* lnb  = (const float*)d_in[28];
    float* out = (float*)d_out;
    float* ws  = (float*)d_ws;

    float* tmp1  = ws;                  // 12288
    float* stats = ws + 12288;          // 1024
    float* At    = ws + 13312;          // 2304
    float* rhs   = ws + 15616;          // 98304
    float* resT  = ws + 113920;         // 4096
    float* xtT   = ws + 118016;         // 6291456
    float* enhT  = ws + 6409472;        // 3145728
    float* F     = ws + 9555200;        // 6291456
    float* xc    = ws + 15846656;       // 29360128  (end: 45206784 floats = 181 MB)

    hipMemsetAsync(ws, 0, 13312 * sizeof(float), stream);  // tmp1 + stats

    k0_rest<<<16, 256, 0, stream>>>(rw, resT);
    k1a_tmp1<<<192, 256, 0, stream>>>(x, U1, tmp1);
    k1b_rhs<<<2048, 256, 0, stream>>>(x, U3, rhs);
    k2b_enh<<<3072, 256, 0, stream>>>(adj, masks, enhT);
    k1c_att<<<16, 256, 0, stream>>>(tmp1, rhs, U2, be, Ve, At);
    k2_xtt<<<2048, 256, 0, stream>>>(x, At, xtT);
    k3_gcn<<<1536, 256, 0, stream>>>(xtT, enhT, W0, b0, Ws, bs, Wd, bd, F);
    k4_conv<<<2048, 512, 0, stream>>>(F, w3, w5, w7, w9, cb, xc, stats);
    k5_final<<<2048, 256, 0, stream>>>(xc, stats, x, gpw, gpb, gqw, gqb,
                                       fcw, fcb, resT, rb, lnw, lnb, out);
}